// Round 10
// baseline (269.924 us; speedup 1.0000x reference)
//
#include <hip/hip_runtime.h>

#define NH   8
#define NPTS 4
#define BB   8
#define CCH  256
#define HH   64
#define WW   64
#define NPIX 4096   // H*W
#define DH   32     // C/NH

// ---------------------------------------------------------------------------
// Kernel A: coords = softmax-epilogue( query^T @ W_off + b_off ).
// Split-K GEMM: M=32768, J=96, K=256.  Block: BM=64, 256 thr = 2 k-groups
// x (16 tm x 8 tj); each half computes 4m x 12j over its K/2=128, partials
// reduced through LDS, softmax fully in-register on the kg=1 half.
// Per k per thread: 1 ds_read_b128 (A) + 3 ds_read_b128 (W) / 48 FMA.
// All stages natural-layout (query is k-major) -> conflict-free.
// ---------------------------------------------------------------------------
__global__ __launch_bounds__(256)
void kA_gemm(const float* __restrict__ query, const float* __restrict__ W_off,
             const float* __restrict__ b_off, float4* __restrict__ coords)
{
    __shared__ float a_lds[64][68];    // [krow][m]; rows 0-31 kg0, 32-63 kg1
    __shared__ float w_lds[64][100];   // [krow][j]; reused as 64m x 96j reduce buf

    const int t    = threadIdx.x;
    const int bid  = blockIdx.x;
    const int sbid = (bid & 7) * 64 + (bid >> 3);   // XCD: batch-per-XCD
    const int m0   = sbid * 64;
    const int b    = m0 >> 12;
    const int n0   = m0 & (NPIX - 1);
    const float* qbase = query + (size_t)b * CCH * NPIX + n0;

    const int kg = t >> 7;        // k-group 0/1 (wave-uniform)
    const int tl = t & 127;
    const int tm = tl >> 3;       // 0..15 -> rows 4*tm..4*tm+3
    const int tj = tl & 7;        // head; j-cols tj*12..tj*12+11

    float acc[4][12];
#pragma unroll
    for (int i = 0; i < 4; ++i)
#pragma unroll
        for (int j = 0; j < 12; ++j) acc[i][j] = 0.f;

    for (int kc = 0; kc < 128; kc += 32) {
        // stage 64 k-rows (32 per half): A 64x64 = 1024 f4, W 64x96 = 1536 f4
        float4 a[4];
#pragma unroll
        for (int ii = 0; ii < 4; ++ii) {
            const int idx = t + ii * 256;            // 0..1023
            const int lr = idx >> 4, m4 = idx & 15;  // lds row, m-quad
            const int gk = ((lr >> 5) << 7) + kc + (lr & 31);
            a[ii] = *(const float4*)(qbase + (size_t)gk * NPIX + (m4 << 2));
        }
        float4 w[6];
#pragma unroll
        for (int ii = 0; ii < 6; ++ii) {
            const int idx = t + ii * 256;            // 0..1535
            const int lr = idx / 24, q = idx - lr * 24;
            const int gk = ((lr >> 5) << 7) + kc + (lr & 31);
            w[ii] = *(const float4*)(W_off + (size_t)gk * 96 + (q << 2));
        }
        __syncthreads();   // previous chunk fully consumed
#pragma unroll
        for (int ii = 0; ii < 4; ++ii) {
            const int idx = t + ii * 256;
            *(float4*)&a_lds[idx >> 4][(idx & 15) << 2] = a[ii];
        }
#pragma unroll
        for (int ii = 0; ii < 6; ++ii) {
            const int idx = t + ii * 256;
            const int lr = idx / 24, q = idx - lr * 24;
            *(float4*)&w_lds[lr][q << 2] = w[ii];
        }
        __syncthreads();

        const int kr0 = kg << 5;
#pragma unroll
        for (int kk = 0; kk < 32; ++kk) {
            const int kr = kr0 + kk;
            const float4 av = *(const float4*)&a_lds[kr][tm << 2];
            const float4 w0 = *(const float4*)&w_lds[kr][tj * 12];
            const float4 w1 = *(const float4*)&w_lds[kr][tj * 12 + 4];
            const float4 w2 = *(const float4*)&w_lds[kr][tj * 12 + 8];
            const float ar[4]  = {av.x, av.y, av.z, av.w};
            const float wr[12] = {w0.x, w0.y, w0.z, w0.w,
                                  w1.x, w1.y, w1.z, w1.w,
                                  w2.x, w2.y, w2.z, w2.w};
#pragma unroll
            for (int i = 0; i < 4; ++i)
#pragma unroll
                for (int j = 0; j < 12; ++j)
                    acc[i][j] = fmaf(ar[i], wr[j], acc[i][j]);
        }
    }

    // split-K reduction through w_lds (reused as [64 m][96 j])
    __syncthreads();
    if (kg == 0) {
#pragma unroll
        for (int i = 0; i < 4; ++i)
#pragma unroll
            for (int jq = 0; jq < 3; ++jq) {
                float4 v = make_float4(acc[i][jq * 4 + 0], acc[i][jq * 4 + 1],
                                       acc[i][jq * 4 + 2], acc[i][jq * 4 + 3]);
                *(float4*)&w_lds[(tm << 2) + i][tj * 12 + (jq << 2)] = v;
            }
    }
    __syncthreads();
    if (kg == 1) {
#pragma unroll
        for (int i = 0; i < 4; ++i)
#pragma unroll
            for (int jq = 0; jq < 3; ++jq) {
                const float4 v = *(const float4*)&w_lds[(tm << 2) + i][tj * 12 + (jq << 2)];
                acc[i][jq * 4 + 0] += v.x;
                acc[i][jq * 4 + 1] += v.y;
                acc[i][jq * 4 + 2] += v.z;
                acc[i][jq * 4 + 3] += v.w;
            }

        float bo[12];
#pragma unroll
        for (int j = 0; j < 12; ++j) bo[j] = b_off[tj * 12 + j];

#pragma unroll
        for (int i = 0; i < 4; ++i) {
            const int g = m0 + (tm << 2) + i;       // global pixel id
            const int n = g & (NPIX - 1);
            const float fx = (float)(n & 63), fy = (float)(n >> 6);

            float ox[4], oy[4], l[4];
#pragma unroll
            for (int p = 0; p < 4; ++p) {
                ox[p] = acc[i][p * 3 + 0] + bo[p * 3 + 0];
                oy[p] = acc[i][p * 3 + 1] + bo[p * 3 + 1];
                l[p]  = acc[i][p * 3 + 2] + bo[p * 3 + 2];
            }
            float m = fmaxf(fmaxf(l[0], l[1]), fmaxf(l[2], l[3]));
            float e[4], s = 0.f;
#pragma unroll
            for (int p = 0; p < 4; ++p) { e[p] = __expf(l[p] - m); s += e[p]; }
            const float inv = 1.f / s;

            float4* cp = coords + ((size_t)g * NH + tj) * NPTS;
#pragma unroll
            for (int p = 0; p < 4; ++p)
                cp[p] = make_float4(fx + ox[p] * 3.15f, fy + oy[p] * 3.15f,
                                    e[p] * inv, 0.f);
        }
    }
}

// ---------------------------------------------------------------------------
// Kernel T: transpose key [b][c][n] -> keyT [b][n][c]  (channel-last)
// ---------------------------------------------------------------------------
__global__ __launch_bounds__(256)
void kT_transpose(const float* __restrict__ key, float* __restrict__ keyT)
{
    __shared__ float tile[64][65];
    int bid = blockIdx.x;                  // B*4*64 = 2048
    const int nt = bid & 63; bid >>= 6;
    const int ct = bid & 3;  bid >>= 2;
    const int b  = bid;
    const int n0 = nt * 64, c0 = ct * 64;
    const int t = threadIdx.x;

    const float* src = key + ((size_t)b * CCH + c0) * NPIX + n0;
#pragma unroll
    for (int ii = 0; ii < 4; ++ii) {
        int idx = t + ii * 256;
        int cc = idx >> 4, q = idx & 15;
        float4 v = *(const float4*)(src + (size_t)cc * NPIX + (q << 2));
        tile[cc][(q << 2) + 0] = v.x;
        tile[cc][(q << 2) + 1] = v.y;
        tile[cc][(q << 2) + 2] = v.z;
        tile[cc][(q << 2) + 3] = v.w;
    }
    __syncthreads();
    float* dst = keyT + ((size_t)(b * NPIX + n0)) * CCH + c0;
#pragma unroll
    for (int ii = 0; ii < 4; ++ii) {
        int idx = t + ii * 256;
        int nn = idx >> 4, q = idx & 15;
        float4 v = make_float4(tile[(q << 2) + 0][nn], tile[(q << 2) + 1][nn],
                               tile[(q << 2) + 2][nn], tile[(q << 2) + 3][nn]);
        *(float4*)(dst + (size_t)nn * CCH + (q << 2)) = v;
    }
}

// ---------------------------------------------------------------------------
// Kernel B: channel-last gather.  Wave = 1 pixel x 8 heads; lanegroup of
// 8 lanes per head, each lane owns 4 channels (float4).  No LDS, no sync.
// XCD swizzle: XCD i sees only batch i -> 4 MB keyT slice L2-resident.
// ---------------------------------------------------------------------------
__global__ __launch_bounds__(256)
void kB_gather(const float* __restrict__ keyT, const float4* __restrict__ coords,
               float* __restrict__ feat)
{
    const int bid  = blockIdx.x;
    const int sbid = (bid & 7) * 1024 + (bid >> 3);

    const int t  = threadIdx.x;
    const int wv = t >> 6, l = t & 63;
    const int g  = sbid * 4 + wv;          // global pixel id, 0..32767
    const int b  = g >> 12;
    const int head = l >> 3;
    const int cl   = (l & 7) << 2;
    const int c    = head * DH + cl;

    const float*  kb = keyT + (((size_t)b << 12)) * CCH;
    const float4* cp = coords + ((size_t)g * NH + head) * NPTS;

    float4 acc = make_float4(0.f, 0.f, 0.f, 0.f);
#pragma unroll
    for (int pt = 0; pt < 4; ++pt) {
        float4 co = cp[pt];
        float xp = co.x, yp = co.y, wgt = co.z;
        float x0f = floorf(xp), y0f = floorf(yp);
        int   x0  = (int)x0f,  y0  = (int)y0f;
        float wx  = xp - x0f,  wy  = yp - y0f;
#pragma unroll
        for (int cr = 0; cr < 4; ++cr) {
            int   xi = x0 + (cr & 1);
            int   yi = y0 + (cr >> 1);
            float wc = ((cr & 1) ? wx : 1.f - wx) * ((cr >> 1) ? wy : 1.f - wy);
            bool  valid = (xi >= 0) && (xi < WW) && (yi >= 0) && (yi < HH);
            int   xc = min(max(xi, 0), WW - 1);
            int   yc = min(max(yi, 0), HH - 1);
            float ww = valid ? (wgt * wc) : 0.f;
            float4 v = *(const float4*)(kb + ((size_t)((yc << 6) + xc)) * CCH + c);
            acc.x = fmaf(ww, v.x, acc.x);
            acc.y = fmaf(ww, v.y, acc.y);
            acc.z = fmaf(ww, v.z, acc.z);
            acc.w = fmaf(ww, v.w, acc.w);
        }
    }
    *(float4*)(feat + (size_t)g * CCH + c) = acc;
}

// ---------------------------------------------------------------------------
// Kernel B (fallback): scalar strided gather from original key layout
// ---------------------------------------------------------------------------
__global__ __launch_bounds__(256)
void kB_sample(const float* __restrict__ key, const float4* __restrict__ coords,
               float* __restrict__ feat)
{
    __shared__ float cx[4][64], cy[4][64], cw[4][64];

    const int t = threadIdx.x;
    int bi = blockIdx.x;
    const int y    = bi & 63; bi >>= 6;
    const int head = bi & 7;  bi >>= 3;
    const int b    = bi;

    {
        const int xx = t >> 2, pt = t & 3;
        float4 v = coords[((size_t)(b * NPIX + y * WW + xx) * NH + head) * NPTS + pt];
        cx[pt][xx] = v.x; cy[pt][xx] = v.y; cw[pt][xx] = v.z;
    }
    __syncthreads();

    const int x  = t & 63;
    const int cg = t >> 6;
    const int c0 = head * DH + cg * 8;
    const float* kbase = key + ((size_t)b * CCH + c0) * NPIX;

    float acc[8];
#pragma unroll
    for (int i = 0; i < 8; ++i) acc[i] = 0.f;

#pragma unroll
    for (int pt = 0; pt < 4; ++pt) {
        float xp = cx[pt][x], yp = cy[pt][x], wgt = cw[pt][x];
        float x0f = floorf(xp), y0f = floorf(yp);
        int   x0  = (int)x0f,  y0  = (int)y0f;
        float wx  = xp - x0f,  wy  = yp - y0f;
#pragma unroll
        for (int cr = 0; cr < 4; ++cr) {
            int   xi = x0 + (cr & 1);
            int   yi = y0 + (cr >> 1);
            float wc = ((cr & 1) ? wx : 1.f - wx) * ((cr >> 1) ? wy : 1.f - wy);
            bool  valid = (xi >= 0) && (xi < WW) && (yi >= 0) && (yi < HH);
            int   xc = min(max(xi, 0), WW - 1);
            int   yc = min(max(yi, 0), HH - 1);
            const float* p = kbase + yc * WW + xc;
            float ww = valid ? (wgt * wc) : 0.f;
#pragma unroll
            for (int c = 0; c < 8; ++c)
                acc[c] = fmaf(ww, p[(size_t)c * NPIX], acc[c]);
        }
    }

    float* fp = feat + (size_t)(b * NPIX + y * WW + x) * CCH + c0;
    *(float4*)fp       = make_float4(acc[0], acc[1], acc[2], acc[3]);
    *(float4*)(fp + 4) = make_float4(acc[4], acc[5], acc[6], acc[7]);
}

// ---------------------------------------------------------------------------
// Kernel C: out = feat @ W_proj + b_proj.  64x128 tile, 4m x 8n per thread,
// BK=32.  A staged NATURALLY as a_lds[m][k] (feat is row-major -> direct
// copy, uniform-bank stores, zero conflicts); A read as b128 per 4-k group
// (16-lane broadcast).  Grid 1024 -> 4 blocks/CU.
// ---------------------------------------------------------------------------
__global__ __launch_bounds__(256)
void kC_proj(const float* __restrict__ feat, const float* __restrict__ W_proj,
             const float* __restrict__ b_proj, float* __restrict__ out)
{
    __shared__ float a_lds[64][36];    // [m][k], pad 32->36
    __shared__ float b_lds[32][128];   // [k][n]

    const int t    = threadIdx.x;
    const int bid  = blockIdx.x;
    const int sbid = (bid & 7) * 128 + (bid >> 3);  // XCD: contiguous feat panels
    const int mb = sbid >> 1;
    const int nb = sbid & 1;
    const int m0 = mb * 64, n0 = nb * 128;

    const int tm = t >> 4, tn = t & 15;

    float acc[4][8];
#pragma unroll
    for (int i = 0; i < 4; ++i)
#pragma unroll
        for (int j = 0; j < 8; ++j) acc[i][j] = 0.f;

    for (int kc = 0; kc < 256; kc += 32) {
        // A: 64 m x 8 k-quads = 512 f4 / 256 thr = 2 each
        float4 a[2];
#pragma unroll
        for (int ii = 0; ii < 2; ++ii) {
            const int idx = t + ii * 256;
            a[ii] = *(const float4*)(feat + (size_t)(m0 + (idx >> 3)) * 256
                                     + kc + ((idx & 7) << 2));
        }
        // B: 32 k x 32 n-quads = 1024 f4 / 256 thr = 4 each
        float4 w[4];
#pragma unroll
        for (int ii = 0; ii < 4; ++ii) {
            const int idx = t + ii * 256;
            w[ii] = *(const float4*)(W_proj + (size_t)(kc + (idx >> 5)) * 256
                                     + n0 + ((idx & 31) << 2));
        }
        __syncthreads();   // previous chunk fully consumed
#pragma unroll
        for (int ii = 0; ii < 2; ++ii) {
            const int idx = t + ii * 256;
            *(float4*)&a_lds[idx >> 3][(idx & 7) << 2] = a[ii];   // direct copy
        }
#pragma unroll
        for (int ii = 0; ii < 4; ++ii) {
            const int idx = t + ii * 256;
            *(float4*)&b_lds[idx >> 5][(idx & 31) << 2] = w[ii];
        }
        __syncthreads();
#pragma unroll
        for (int k4 = 0; k4 < 8; ++k4) {
            float ar[4][4];
#pragma unroll
            for (int i = 0; i < 4; ++i) {
                const float4 av = *(const float4*)&a_lds[(tm << 2) + i][k4 << 2];
                ar[i][0] = av.x; ar[i][1] = av.y; ar[i][2] = av.z; ar[i][3] = av.w;
            }
#pragma unroll
            for (int kk = 0; kk < 4; ++kk) {
                const int k = (k4 << 2) + kk;
                const float4 bv0 = *(const float4*)&b_lds[k][tn << 2];
                const float4 bv1 = *(const float4*)&b_lds[k][64 + (tn << 2)];
                const float br[8] = {bv0.x, bv0.y, bv0.z, bv0.w,
                                     bv1.x, bv1.y, bv1.z, bv1.w};
#pragma unroll
                for (int i = 0; i < 4; ++i)
#pragma unroll
                    for (int j = 0; j < 8; ++j)
                        acc[i][j] = fmaf(ar[i][kk], br[j], acc[i][j]);
            }
        }
    }

    const float4 bp0 = *(const float4*)(b_proj + n0 + (tn << 2));
    const float4 bp1 = *(const float4*)(b_proj + n0 + 64 + (tn << 2));
#pragma unroll
    for (int i = 0; i < 4; ++i) {
        float* op = out + (size_t)(m0 + (tm << 2) + i) * 256 + n0;
        *(float4*)(op + (tn << 2)) =
            make_float4(acc[i][0] + bp0.x, acc[i][1] + bp0.y,
                        acc[i][2] + bp0.z, acc[i][3] + bp0.w);
        *(float4*)(op + 64 + (tn << 2)) =
            make_float4(acc[i][4] + bp1.x, acc[i][5] + bp1.y,
                        acc[i][6] + bp1.z, acc[i][7] + bp1.w);
    }
}

// ---------------------------------------------------------------------------
extern "C" void kernel_launch(void* const* d_in, const int* in_sizes, int n_in,
                              void* d_out, int out_size, void* d_ws, size_t ws_size,
                              hipStream_t stream)
{
    const float* query  = (const float*)d_in[0];
    const float* key    = (const float*)d_in[1];
    const float* W_off  = (const float*)d_in[2];
    const float* b_off  = (const float*)d_in[3];
    const float* W_proj = (const float*)d_in[4];
    const float* b_proj = (const float*)d_in[5];
    float* out = (float*)d_out;

    const size_t keyT_bytes   = (size_t)BB * NPIX * CCH * sizeof(float);          // 33.55 MB
    const size_t coords_bytes = (size_t)BB * NPIX * NH * NPTS * sizeof(float4);   // 16.78 MB
    const size_t feat_bytes   = (size_t)BB * NPIX * CCH * sizeof(float);          // 33.55 MB

    if (ws_size >= keyT_bytes + coords_bytes + feat_bytes) {
        float*  keyT   = (float*)d_ws;
        float4* coords = (float4*)((char*)d_ws + keyT_bytes);
        float*  feat   = (float*)((char*)d_ws + keyT_bytes + coords_bytes);

        kA_gemm<<<(BB * NPIX) / 64, 256, 0, stream>>>(query, W_off, b_off, coords);
        kT_transpose<<<BB * 4 * 64, 256, 0, stream>>>(key, keyT);
        kB_gather<<<(BB * NPIX) / 4, 256, 0, stream>>>(keyT, coords, feat);
        kC_proj<<<(BB * NPIX / 64) * 2, 256, 0, stream>>>(feat, W_proj, b_proj, out);
    } else {
        // fallback path (needs 50.3 MB)
        float4* coords = (float4*)d_ws;
        float*  feat   = (float*)((char*)d_ws + coords_bytes);

        kA_gemm<<<(BB * NPIX) / 64, 256, 0, stream>>>(query, W_off, b_off, coords);
        kB_sample<<<BB * NH * HH, 256, 0, stream>>>(key, coords, feat);
        kC_proj<<<(BB * NPIX / 64) * 2, 256, 0, stream>>>(feat, W_proj, b_proj, out);
    }
}

// Round 11
// 236.169 us; speedup vs baseline: 1.1429x; 1.1429x over previous
//
#include <hip/hip_runtime.h>
#include <hip/hip_bf16.h>

#define NH   8
#define NPTS 4
#define BB   8
#define CCH  256
#define HH   64
#define WW   64
#define NPIX 4096   // H*W
#define DH   32     // C/NH

typedef __attribute__((ext_vector_type(8))) short bf16x8;
typedef __attribute__((ext_vector_type(4))) float f32x4;

__device__ __forceinline__ ushort f2bf(float x) {
    union { __hip_bfloat16 b; ushort u; } c; c.b = __float2bfloat16(x); return c.u;
}
__device__ __forceinline__ float bf2f(ushort u) {
    union { __hip_bfloat16 b; ushort u; } c; c.u = u; return __bfloat162float(c.b);
}

// ---------------------------------------------------------------------------
// Kernel A: coords = softmax-epilogue( query^T @ W_off + b_off ).
// (unchanged from round 10 — measured-neutral split-K; MFMA port is next round)
// ---------------------------------------------------------------------------
__global__ __launch_bounds__(256)
void kA_gemm(const float* __restrict__ query, const float* __restrict__ W_off,
             const float* __restrict__ b_off, float4* __restrict__ coords)
{
    __shared__ float a_lds[64][68];    // [krow][m]; rows 0-31 kg0, 32-63 kg1
    __shared__ float w_lds[64][100];   // [krow][j]; reused as 64m x 96j reduce buf

    const int t    = threadIdx.x;
    const int bid  = blockIdx.x;
    const int sbid = (bid & 7) * 64 + (bid >> 3);   // XCD: batch-per-XCD
    const int m0   = sbid * 64;
    const int b    = m0 >> 12;
    const int n0   = m0 & (NPIX - 1);
    const float* qbase = query + (size_t)b * CCH * NPIX + n0;

    const int kg = t >> 7;
    const int tl = t & 127;
    const int tm = tl >> 3;
    const int tj = tl & 7;

    float acc[4][12];
#pragma unroll
    for (int i = 0; i < 4; ++i)
#pragma unroll
        for (int j = 0; j < 12; ++j) acc[i][j] = 0.f;

    for (int kc = 0; kc < 128; kc += 32) {
        float4 a[4];
#pragma unroll
        for (int ii = 0; ii < 4; ++ii) {
            const int idx = t + ii * 256;
            const int lr = idx >> 4, m4 = idx & 15;
            const int gk = ((lr >> 5) << 7) + kc + (lr & 31);
            a[ii] = *(const float4*)(qbase + (size_t)gk * NPIX + (m4 << 2));
        }
        float4 w[6];
#pragma unroll
        for (int ii = 0; ii < 6; ++ii) {
            const int idx = t + ii * 256;
            const int lr = idx / 24, q = idx - lr * 24;
            const int gk = ((lr >> 5) << 7) + kc + (lr & 31);
            w[ii] = *(const float4*)(W_off + (size_t)gk * 96 + (q << 2));
        }
        __syncthreads();
#pragma unroll
        for (int ii = 0; ii < 4; ++ii) {
            const int idx = t + ii * 256;
            *(float4*)&a_lds[idx >> 4][(idx & 15) << 2] = a[ii];
        }
#pragma unroll
        for (int ii = 0; ii < 6; ++ii) {
            const int idx = t + ii * 256;
            const int lr = idx / 24, q = idx - lr * 24;
            *(float4*)&w_lds[lr][q << 2] = w[ii];
        }
        __syncthreads();

        const int kr0 = kg << 5;
#pragma unroll
        for (int kk = 0; kk < 32; ++kk) {
            const int kr = kr0 + kk;
            const float4 av = *(const float4*)&a_lds[kr][tm << 2];
            const float4 w0 = *(const float4*)&w_lds[kr][tj * 12];
            const float4 w1 = *(const float4*)&w_lds[kr][tj * 12 + 4];
            const float4 w2 = *(const float4*)&w_lds[kr][tj * 12 + 8];
            const float ar[4]  = {av.x, av.y, av.z, av.w};
            const float wr[12] = {w0.x, w0.y, w0.z, w0.w,
                                  w1.x, w1.y, w1.z, w1.w,
                                  w2.x, w2.y, w2.z, w2.w};
#pragma unroll
            for (int i = 0; i < 4; ++i)
#pragma unroll
                for (int j = 0; j < 12; ++j)
                    acc[i][j] = fmaf(ar[i], wr[j], acc[i][j]);
        }
    }

    __syncthreads();
    if (kg == 0) {
#pragma unroll
        for (int i = 0; i < 4; ++i)
#pragma unroll
            for (int jq = 0; jq < 3; ++jq) {
                float4 v = make_float4(acc[i][jq * 4 + 0], acc[i][jq * 4 + 1],
                                       acc[i][jq * 4 + 2], acc[i][jq * 4 + 3]);
                *(float4*)&w_lds[(tm << 2) + i][tj * 12 + (jq << 2)] = v;
            }
    }
    __syncthreads();
    if (kg == 1) {
#pragma unroll
        for (int i = 0; i < 4; ++i)
#pragma unroll
            for (int jq = 0; jq < 3; ++jq) {
                const float4 v = *(const float4*)&w_lds[(tm << 2) + i][tj * 12 + (jq << 2)];
                acc[i][jq * 4 + 0] += v.x;
                acc[i][jq * 4 + 1] += v.y;
                acc[i][jq * 4 + 2] += v.z;
                acc[i][jq * 4 + 3] += v.w;
            }

        float bo[12];
#pragma unroll
        for (int j = 0; j < 12; ++j) bo[j] = b_off[tj * 12 + j];

#pragma unroll
        for (int i = 0; i < 4; ++i) {
            const int g = m0 + (tm << 2) + i;
            const int n = g & (NPIX - 1);
            const float fx = (float)(n & 63), fy = (float)(n >> 6);

            float ox[4], oy[4], lg[4];
#pragma unroll
            for (int p = 0; p < 4; ++p) {
                ox[p] = acc[i][p * 3 + 0] + bo[p * 3 + 0];
                oy[p] = acc[i][p * 3 + 1] + bo[p * 3 + 1];
                lg[p] = acc[i][p * 3 + 2] + bo[p * 3 + 2];
            }
            float m = fmaxf(fmaxf(lg[0], lg[1]), fmaxf(lg[2], lg[3]));
            float e[4], s = 0.f;
#pragma unroll
            for (int p = 0; p < 4; ++p) { e[p] = __expf(lg[p] - m); s += e[p]; }
            const float inv = 1.f / s;

            float4* cp = coords + ((size_t)g * NH + tj) * NPTS;
#pragma unroll
            for (int p = 0; p < 4; ++p)
                cp[p] = make_float4(fx + ox[p] * 3.15f, fy + oy[p] * 3.15f,
                                    e[p] * inv, 0.f);
        }
    }
}

// ---------------------------------------------------------------------------
// Kernel T: transpose key [b][c][n] -> keyT [b][n][c]  (channel-last)
// ---------------------------------------------------------------------------
__global__ __launch_bounds__(256)
void kT_transpose(const float* __restrict__ key, float* __restrict__ keyT)
{
    __shared__ float tile[64][65];
    int bid = blockIdx.x;                  // B*4*64 = 2048
    const int nt = bid & 63; bid >>= 6;
    const int ct = bid & 3;  bid >>= 2;
    const int b  = bid;
    const int n0 = nt * 64, c0 = ct * 64;
    const int t = threadIdx.x;

    const float* src = key + ((size_t)b * CCH + c0) * NPIX + n0;
#pragma unroll
    for (int ii = 0; ii < 4; ++ii) {
        int idx = t + ii * 256;
        int cc = idx >> 4, q = idx & 15;
        float4 v = *(const float4*)(src + (size_t)cc * NPIX + (q << 2));
        tile[cc][(q << 2) + 0] = v.x;
        tile[cc][(q << 2) + 1] = v.y;
        tile[cc][(q << 2) + 2] = v.z;
        tile[cc][(q << 2) + 3] = v.w;
    }
    __syncthreads();
    float* dst = keyT + ((size_t)(b * NPIX + n0)) * CCH + c0;
#pragma unroll
    for (int ii = 0; ii < 4; ++ii) {
        int idx = t + ii * 256;
        int nn = idx >> 4, q = idx & 15;
        float4 v = make_float4(tile[(q << 2) + 0][nn], tile[(q << 2) + 1][nn],
                               tile[(q << 2) + 2][nn], tile[(q << 2) + 3][nn]);
        *(float4*)(dst + (size_t)nn * CCH + (q << 2)) = v;
    }
}

// ---------------------------------------------------------------------------
// Kernel B: channel-last gather -> feat emitted as bf16 hi/lo pair
// (same bytes/value as fp32: 2B hi + 2B lo).  Wave = 1 pixel x 8 heads.
// ---------------------------------------------------------------------------
__global__ __launch_bounds__(256)
void kB_gather(const float* __restrict__ keyT, const float4* __restrict__ coords,
               ushort* __restrict__ featH, ushort* __restrict__ featL)
{
    const int bid  = blockIdx.x;
    const int sbid = (bid & 7) * 1024 + (bid >> 3);

    const int t  = threadIdx.x;
    const int wv = t >> 6, l = t & 63;
    const int g  = sbid * 4 + wv;          // global pixel id, 0..32767
    const int b  = g >> 12;
    const int head = l >> 3;
    const int cl   = (l & 7) << 2;
    const int c    = head * DH + cl;

    const float*  kb = keyT + (((size_t)b << 12)) * CCH;
    const float4* cp = coords + ((size_t)g * NH + head) * NPTS;

    float4 acc = make_float4(0.f, 0.f, 0.f, 0.f);
#pragma unroll
    for (int pt = 0; pt < 4; ++pt) {
        float4 co = cp[pt];
        float xp = co.x, yp = co.y, wgt = co.z;
        float x0f = floorf(xp), y0f = floorf(yp);
        int   x0  = (int)x0f,  y0  = (int)y0f;
        float wx  = xp - x0f,  wy  = yp - y0f;
#pragma unroll
        for (int cr = 0; cr < 4; ++cr) {
            int   xi = x0 + (cr & 1);
            int   yi = y0 + (cr >> 1);
            float wc = ((cr & 1) ? wx : 1.f - wx) * ((cr >> 1) ? wy : 1.f - wy);
            bool  valid = (xi >= 0) && (xi < WW) && (yi >= 0) && (yi < HH);
            int   xc = min(max(xi, 0), WW - 1);
            int   yc = min(max(yi, 0), HH - 1);
            float ww = valid ? (wgt * wc) : 0.f;
            float4 v = *(const float4*)(kb + ((size_t)((yc << 6) + xc)) * CCH + c);
            acc.x = fmaf(ww, v.x, acc.x);
            acc.y = fmaf(ww, v.y, acc.y);
            acc.z = fmaf(ww, v.z, acc.z);
            acc.w = fmaf(ww, v.w, acc.w);
        }
    }
    const float a4[4] = {acc.x, acc.y, acc.z, acc.w};
    ushort hs[4], ls[4];
#pragma unroll
    for (int j = 0; j < 4; ++j) {
        hs[j] = f2bf(a4[j]);
        ls[j] = f2bf(a4[j] - bf2f(hs[j]));
    }
    *(ushort4*)(featH + (size_t)g * CCH + c) = make_ushort4(hs[0], hs[1], hs[2], hs[3]);
    *(ushort4*)(featL + (size_t)g * CCH + c) = make_ushort4(ls[0], ls[1], ls[2], ls[3]);
}

// ---------------------------------------------------------------------------
// Kernel W: W_proj [k][n] fp32 -> WT hi/lo [n][k] bf16 (k-contiguous).
// 256x256, grid 16 of 64x64 tiles.
// ---------------------------------------------------------------------------
__global__ __launch_bounds__(256)
void kW_conv(const float* __restrict__ W, ushort* __restrict__ WTh,
             ushort* __restrict__ WTl)
{
    __shared__ float tile[64][65];
    const int t  = threadIdx.x;
    const int kt = blockIdx.x >> 2, nt = blockIdx.x & 3;
    const int k0 = kt * 64, n0 = nt * 64;

    const float* src = W + (size_t)k0 * 256 + n0;
#pragma unroll
    for (int ii = 0; ii < 4; ++ii) {
        int idx = t + ii * 256;
        int kk = idx >> 4, q = idx & 15;
        float4 v = *(const float4*)(src + (size_t)kk * 256 + (q << 2));
        tile[kk][(q << 2) + 0] = v.x;
        tile[kk][(q << 2) + 1] = v.y;
        tile[kk][(q << 2) + 2] = v.z;
        tile[kk][(q << 2) + 3] = v.w;
    }
    __syncthreads();
#pragma unroll
    for (int ii = 0; ii < 4; ++ii) {
        int idx = t + ii * 256;
        int nn = idx >> 4, q = idx & 15;
        float xs[4] = { tile[(q << 2) + 0][nn], tile[(q << 2) + 1][nn],
                        tile[(q << 2) + 2][nn], tile[(q << 2) + 3][nn] };
        ushort hs[4], ls[4];
#pragma unroll
        for (int j = 0; j < 4; ++j) {
            hs[j] = f2bf(xs[j]);
            ls[j] = f2bf(xs[j] - bf2f(hs[j]));
        }
        *(ushort4*)(WTh + (size_t)(n0 + nn) * 256 + k0 + (q << 2)) =
            make_ushort4(hs[0], hs[1], hs[2], hs[3]);
        *(ushort4*)(WTl + (size_t)(n0 + nn) * 256 + k0 + (q << 2)) =
            make_ushort4(ls[0], ls[1], ls[2], ls[3]);
    }
}

// ---------------------------------------------------------------------------
// Kernel C: out = feat @ W_proj + b_proj via bf16x3 split-precision MFMA.
// 128x128 tile, BK=32, 4 waves (2x2 of 64x64).  A = feat hi/lo [m][k];
// B = WT hi/lo [n][k].  acc += Ah*Bh + Ah*Bl + Al*Bh (Al*Bl ~2^-16, dropped).
// Frag layout (AMD matrix core, 16x16x32): A row=l&15 k=8*(l>>4)+i;
// B col=l&15 same k; C col=l&15 row=4*(l>>4)+reg (m89-verified).
// ---------------------------------------------------------------------------
__global__ __launch_bounds__(256)
void kC_mfma(const ushort* __restrict__ featH, const ushort* __restrict__ featL,
             const ushort* __restrict__ WTh, const ushort* __restrict__ WTl,
             const float* __restrict__ b_proj, float* __restrict__ out)
{
    __shared__ __align__(16) ushort Ah[128][40];   // pad 32->40 (80B rows, 16B-mult)
    __shared__ __align__(16) ushort Al[128][40];
    __shared__ __align__(16) ushort Bh[128][40];
    __shared__ __align__(16) ushort Bl[128][40];

    const int t  = threadIdx.x;
    const int mb = blockIdx.x >> 1;
    const int nb = blockIdx.x & 1;
    const int m0 = mb * 128, n0 = nb * 128;
    const int w  = t >> 6, l = t & 63;
    const int wr = w >> 1, wc = w & 1;       // wave -> 64x64 quadrant
    const int lr = l & 15;                   // frag row (A) / col (B)
    const int lk = (l >> 4) << 3;            // frag k-offset (8 bf16)

    f32x4 acc[4][4];
#pragma unroll
    for (int i = 0; i < 4; ++i)
#pragma unroll
        for (int j = 0; j < 4; ++j) acc[i][j] = (f32x4){0.f, 0.f, 0.f, 0.f};

    for (int kc = 0; kc < 256; kc += 32) {
        // stage: each array 128 rows x 32k bf16 = 512 x 16B; 2 slots/thread
        uint4 ra[2], rla[2], rb[2], rlb[2];
#pragma unroll
        for (int ii = 0; ii < 2; ++ii) {
            const int idx = t + ii * 256;
            const int row = idx >> 2, q = idx & 3;
            ra[ii]  = *(const uint4*)(featH + (size_t)(m0 + row) * 256 + kc + (q << 3));
            rla[ii] = *(const uint4*)(featL + (size_t)(m0 + row) * 256 + kc + (q << 3));
            rb[ii]  = *(const uint4*)(WTh   + (size_t)(n0 + row) * 256 + kc + (q << 3));
            rlb[ii] = *(const uint4*)(WTl   + (size_t)(n0 + row) * 256 + kc + (q << 3));
        }
        __syncthreads();   // prior chunk's frag reads complete
#pragma unroll
        for (int ii = 0; ii < 2; ++ii) {
            const int idx = t + ii * 256;
            const int row = idx >> 2, q = idx & 3;
            *(uint4*)&Ah[row][q << 3] = ra[ii];
            *(uint4*)&Al[row][q << 3] = rla[ii];
            *(uint4*)&Bh[row][q << 3] = rb[ii];
            *(uint4*)&Bl[row][q << 3] = rlb[ii];
        }
        __syncthreads();

        bf16x8 fb[4], fbl[4];
#pragma unroll
        for (int nf = 0; nf < 4; ++nf) {
            fb[nf]  = *(const bf16x8*)&Bh[wc * 64 + nf * 16 + lr][lk];
            fbl[nf] = *(const bf16x8*)&Bl[wc * 64 + nf * 16 + lr][lk];
        }
#pragma unroll
        for (int mf = 0; mf < 4; ++mf) {
            const bf16x8 fa  = *(const bf16x8*)&Ah[wr * 64 + mf * 16 + lr][lk];
            const bf16x8 fal = *(const bf16x8*)&Al[wr * 64 + mf * 16 + lr][lk];
#pragma unroll
            for (int nf = 0; nf < 4; ++nf) {
                acc[mf][nf] = __builtin_amdgcn_mfma_f32_16x16x32_bf16(
                                  fa, fb[nf], acc[mf][nf], 0, 0, 0);
                acc[mf][nf] = __builtin_amdgcn_mfma_f32_16x16x32_bf16(
                                  fa, fbl[nf], acc[mf][nf], 0, 0, 0);
                acc[mf][nf] = __builtin_amdgcn_mfma_f32_16x16x32_bf16(
                                  fal, fb[nf], acc[mf][nf], 0, 0, 0);
            }
        }
    }

    // epilogue: C col = lane&15, row = 4*(lane>>4)+reg
    const int r4 = (l >> 4) << 2;
#pragma unroll
    for (int nf = 0; nf < 4; ++nf) {
        const int col = n0 + wc * 64 + nf * 16 + lr;
        const float bp = b_proj[col];
#pragma unroll
        for (int mf = 0; mf < 4; ++mf) {
            const int row = m0 + wr * 64 + mf * 16 + r4;
            const f32x4 v = acc[mf][nf];
            out[(size_t)(row + 0) * 256 + col] = v.x + bp;
            out[(size_t)(row + 1) * 256 + col] = v.y + bp;
            out[(size_t)(row + 2) * 256 + col] = v.z + bp;
            out[(size_t)(row + 3) * 256 + col] = v.w + bp;
        }
    }
}

// ---------------------------------------------------------------------------
extern "C" void kernel_launch(void* const* d_in, const int* in_sizes, int n_in,
                              void* d_out, int out_size, void* d_ws, size_t ws_size,
                              hipStream_t stream)
{
    const float* query  = (const float*)d_in[0];
    const float* key    = (const float*)d_in[1];
    const float* W_off  = (const float*)d_in[2];
    const float* b_off  = (const float*)d_in[3];
    const float* W_proj = (const float*)d_in[4];
    const float* b_proj = (const float*)d_in[5];
    float* out = (float*)d_out;

    // workspace (83.886 MB total — same size as the proven round-2..10 layout):
    // [keyT 33.55M][coords 16.78M][featH 16.78M][featL 16.78M]
    // WT hi/lo (256 KB) overlays keyT's space; written by kW AFTER kB consumes keyT.
    const size_t keyT_bytes   = (size_t)BB * NPIX * CCH * sizeof(float);
    const size_t coords_bytes = (size_t)BB * NPIX * NH * NPTS * sizeof(float4);
    const size_t feat_bytes   = (size_t)BB * NPIX * CCH * sizeof(ushort);

    char* p = (char*)d_ws;
    float*  keyT   = (float*)p;
    ushort* WTh    = (ushort*)p;                       // after kB
    ushort* WTl    = (ushort*)(p + 131072);
    float4* coords = (float4*)(p + keyT_bytes);
    ushort* featH  = (ushort*)(p + keyT_bytes + coords_bytes);
    ushort* featL  = (ushort*)(p + keyT_bytes + coords_bytes + feat_bytes);

    kA_gemm<<<(BB * NPIX) / 64, 256, 0, stream>>>(query, W_off, b_off, coords);
    kT_transpose<<<BB * 4 * 64, 256, 0, stream>>>(key, keyT);
    kB_gather<<<(BB * NPIX) / 4, 256, 0, stream>>>(keyT, coords, featH, featL);
    kW_conv<<<16, 256, 0, stream>>>(W_proj, WTh, WTl);
    kC_mfma<<<(BB * NPIX / 128) * 2, 256, 0, stream>>>(featH, featL, WTh, WTl,
                                                       b_proj, out);
}